// Round 4
// baseline (867.732 us; speedup 1.0000x reference)
//
#include <hip/hip_runtime.h>
#include <hip/hip_bf16.h>

#define NFEAT 300
#define KP 320           // padded feature stride (bf16 rows)
#define NGRAPH 2048
#define N1P 640          // padded N for GEMM1 (600 -> 640)
#define N2P 384          // padded N for GEMM2 (300 -> 384)
#define NTD 18           // bond_type(6) * bond_dir(3)
#define SCAN_B 2048      // elements per scan block (256 thr * 8)

typedef __bf16 bf16x8 __attribute__((ext_vector_type(8)));
typedef float  f32x4  __attribute__((ext_vector_type(4)));
typedef unsigned short u16x8 __attribute__((ext_vector_type(8)));

__device__ __forceinline__ unsigned short f2b(float v) {
    union { float f; unsigned u; } x; x.f = v;
    unsigned r = x.u + 0x7fff + ((x.u >> 16) & 1);   // RNE
    return (unsigned short)(r >> 16);
}
__device__ __forceinline__ float b2f(unsigned short u) {
    union { unsigned u; float f; } x; x.u = ((unsigned)u) << 16;
    return x.f;
}

#define GLD_LDS16(g, l)                                                        \
    __builtin_amdgcn_global_load_lds(                                          \
        (const __attribute__((address_space(1))) void*)(g),                    \
        (__attribute__((address_space(3))) void*)(l), 16, 0, 0)

// ---------------------------------------------------------------------------
// embc[td][c] = emb1[td/3][c] + emb2[td%3][c]  (fp32, [18 x 320], pad cols 0)
// ---------------------------------------------------------------------------
__global__ __launch_bounds__(256) void k_embc(
    const float* __restrict__ emb1, const float* __restrict__ emb2,
    float* __restrict__ embc)
{
    int t = blockIdx.x * blockDim.x + threadIdx.x;
    if (t >= NTD * KP) return;
    int td = t / KP, c = t % KP;
    int t1 = td / 3, d = td % 3;
    embc[t] = (c < NFEAT) ? emb1[t1 * NFEAT + c] + emb2[d * NFEAT + c] : 0.f;
}

// ---------------------------------------------------------------------------
// x fp32 [n x 300] -> xb bf16 [Mpad x 320] (pads zero)
// ---------------------------------------------------------------------------
__global__ __launch_bounds__(256) void k_cvtX(
    const float* __restrict__ x, unsigned short* __restrict__ xb, int n, int Mpad)
{
    int idx = blockIdx.x * blockDim.x + threadIdx.x;
    if (idx >= Mpad * (KP / 8)) return;
    int row = idx / (KP / 8), c0 = (idx % (KP / 8)) * 8;
    unsigned short o[8];
#pragma unroll
    for (int j = 0; j < 8; ++j) {
        int col = c0 + j;
        float v = (row < n && col < NFEAT) ? x[(size_t)row * NFEAT + col] : 0.f;
        o[j] = f2b(v);
    }
    *(uint4*)&xb[(size_t)row * KP + c0] = *(uint4*)o;
}

// ---------------------------------------------------------------------------
// CSR build: deg -> exclusive-scan offsets -> cursor fill, packed records
// ---------------------------------------------------------------------------
__global__ __launch_bounds__(256) void k_zero(int* __restrict__ p, int n)
{
    int i = blockIdx.x * blockDim.x + threadIdx.x;
    if (i < n) p[i] = 0;
}

__global__ __launch_bounds__(256) void k_deg(
    const int* __restrict__ ei, int* __restrict__ deg, int E)
{
    int e = blockIdx.x * blockDim.x + threadIdx.x;
    if (e >= E) return;
    atomicAdd(&deg[ei[E + e]], 1);
}

__global__ __launch_bounds__(256) void k_scan1(
    const int* __restrict__ deg, int* __restrict__ offsets,
    int* __restrict__ bsum, int n)
{
    __shared__ int sh[256];
    int tid = threadIdx.x;
    int base = blockIdx.x * SCAN_B + tid * 8;
    int v[8], run = 0;
#pragma unroll
    for (int j = 0; j < 8; ++j) {
        int i = base + j;
        v[j] = (i < n) ? deg[i] : 0;
        run += v[j];
        v[j] = run;
    }
    sh[tid] = run;
    __syncthreads();
    for (int off = 1; off < 256; off <<= 1) {
        int t = (tid >= off) ? sh[tid - off] : 0;
        __syncthreads();
        sh[tid] += t;
        __syncthreads();
    }
    int excl = sh[tid] - run;
#pragma unroll
    for (int j = 0; j < 8; ++j) {
        int i = base + j;
        if (i < n) offsets[i + 1] = excl + v[j];
    }
    if (tid == 0) bsum[blockIdx.x] = sh[255];
}

__global__ void k_scan2(int* __restrict__ bsum, int nb, int* __restrict__ offsets)
{
    if (threadIdx.x == 0 && blockIdx.x == 0) {
        int run = 0;
        for (int b = 0; b < nb; ++b) { int t = bsum[b]; bsum[b] = run; run += t; }
        offsets[0] = 0;
    }
}

__global__ __launch_bounds__(256) void k_scan3(
    const int* __restrict__ deg, int* __restrict__ offsets,
    const int* __restrict__ bsum, int* __restrict__ cursor, int n)
{
    int i = blockIdx.x * blockDim.x + threadIdx.x;
    if (i >= n) return;
    int fin = offsets[i + 1] + bsum[i / SCAN_B];
    offsets[i + 1] = fin;
    cursor[i] = fin - deg[i];
}

__global__ __launch_bounds__(256) void k_fill(
    const int* __restrict__ ei, const int* __restrict__ ea,
    int* __restrict__ cursor, int* __restrict__ edgerec, int E)
{
    int e = blockIdx.x * blockDim.x + threadIdx.x;
    if (e >= E) return;
    int dst = ei[E + e];
    int pos = atomicAdd(&cursor[dst], 1);
    int src = ei[e];
    int td  = ea[2 * e] * 3 + ea[2 * e + 1];
    edgerec[pos] = src | (td << 20);
}

// ---------------------------------------------------------------------------
// Gather-side aggregation:
// Ab[v] = bf16( h[v] + embc[0] + sum_{e: dst=v} ( h[src_e] + embc[td_e] ) )
// ---------------------------------------------------------------------------
__global__ __launch_bounds__(256) void k_aggr(
    const unsigned short* __restrict__ h,
    const int* __restrict__ offsets, const int* __restrict__ edgerec,
    const float* __restrict__ embc,
    unsigned short* __restrict__ Ab, int n, int Mpad)
{
    int idx = blockIdx.x * blockDim.x + threadIdx.x;
    if (idx >= Mpad * (KP / 8)) return;
    int v = idx / (KP / 8), c0 = (idx % (KP / 8)) * 8;
    unsigned short* outp = &Ab[(size_t)v * KP + c0];
    if (v >= n) {
        *(uint4*)outp = make_uint4(0, 0, 0, 0);
        return;
    }
    float acc[8];
    u16x8 hv = *(const u16x8*)&h[(size_t)v * KP + c0];
    const float* e0 = embc + c0;
#pragma unroll
    for (int j = 0; j < 8; ++j) acc[j] = b2f(hv[j]) + e0[j];

    int beg = offsets[v], end = offsets[v + 1];
    for (int e = beg; e < end; ++e) {
        int rec = edgerec[e];
        int src = rec & 0xFFFFF;
        int td  = rec >> 20;
        u16x8 hs = *(const u16x8*)&h[(size_t)src * KP + c0];
        const float* ee = embc + td * KP + c0;
#pragma unroll
        for (int j = 0; j < 8; ++j) acc[j] += b2f(hs[j]) + ee[j];
    }
    unsigned short o[8];
#pragma unroll
    for (int j = 0; j < 8; ++j) o[j] = f2b(acc[j]);
    *(uint4*)outp = *(uint4*)o;
}

// ---------------------------------------------------------------------------
// Wt[n*Kpad + k] = bf16(W[k*cols + n]) if in range else 0
// ---------------------------------------------------------------------------
__global__ __launch_bounds__(256) void k_cvtW(
    const float* __restrict__ W, unsigned short* __restrict__ Wt,
    int rows, int cols, int Kpad, int Npad)
{
    int t = blockIdx.x * blockDim.x + threadIdx.x;
    if (t >= Npad * Kpad) return;
    int nn = t / Kpad, k = t % Kpad;
    float v = (k < rows && nn < cols) ? W[(size_t)k * cols + nn] : 0.f;
    Wt[t] = f2b(v);
}

// ---------------------------------------------------------------------------
// bf16 MFMA GEMM, grid-parallel + XCD-swizzled + XOR-swizzled LDS.
//
// v5: B (weights) bypasses LDS entirely. R3 accounting: LDS traffic was
// 48 KB/block/K-step (A+B stage-writes + 2x-duplicated ds_reads) =
// ~43 us of the 77 us GEMM2 time -- LDS bandwidth was the binding term,
// not latency (R2/R3's barrier fixes each gained only ~10%). B is a
// 400-480 KB weight matrix read by every block -> permanently
// L2-resident, and its MFMA fragment (16B/lane, row*K + kt*32 + fq*8)
// loads directly global->VGPR. LDS traffic halves (24 KB/step: A stage
// 8 KB + A ds_read 16 KB); LDS footprint 48 -> 24 KB.
//
// Pipeline (counted-vmcnt FIFO, per-thread ops):
//   prologue: Bload(0)[4] ; Astage(0)[2] ; Astage(1)[2]
//   iter kt : wait vmcnt(2)   -- retires A(kt)+B(kt), A(kt+1) in flight
//             s_barrier        -- A(kt) visible block-wide
//             Bload(kt+1)[4]  then  Astage(kt+2)[2]   (order pinned by
//             sched_barrier(0) fences -- the vmcnt math needs B before A)
//             ds_read A-frags(kt) ; 16 MFMA with B-regs(kt)
//   last iter: wait vmcnt(0).
// B regs double-buffered (bc/bn, swapped by 2x-unrolled loop body; NT is
// always even: 10 or 20). Raw s_barrier is sched_barrier(0)-sandwiched;
// asm waits carry "memory" clobbers.
//
// A staging lane L fetches row (L>>2), k-chunk ((L&3) ^ ((L>>3)&3)) -- the
// 4 lanes of a row cover the same contiguous 64B (coalesced), while chunk
// (r,c) lands at LDS slot 4r + (c ^ ((r>>1)&3)); fragment ds_read_b128
// phases then sweep bank groups conflict-free (2-way only, free).
// Epilogue bounces accumulators through LDS for coalesced uint4 stores.
// C = relu(A @ Bt^T + bias). A [Mpad x K] rm bf16, Bt [N x K] rm bf16.
// ---------------------------------------------------------------------------
__global__ __launch_bounds__(256) void k_gemm(
    const unsigned short* __restrict__ Ag, const unsigned short* __restrict__ Bg,
    const float* __restrict__ bias, int bias_n,
    unsigned short* __restrict__ C, int ldc, int store_cols,
    int K, int npass, int MT)
{
    __shared__ unsigned short smem[12288];  // 24 KB: 3 x 8 KB A buffers (epilogue reuses 16 KB)

    int tid  = threadIdx.x;
    int lane = tid & 63, wave = tid >> 6;

    // XCD-swizzle: same panel -> same XCD for all npass column tiles
    int l    = blockIdx.x;
    int xcd  = l & 7;
    int j    = l >> 3;
    int ncol = j % npass;
    int panel= (j / npass) * 8 + xcd;
    if (panel >= MT) return;
    int m0 = panel * 128;

    int wm = (wave >> 1) * 64, wn = (wave & 1) * 64;
    int fr = lane & 15, fq = lane >> 4;          // fragment row / k-chunk
    int colq = lane & 15, rq = (lane >> 4) * 4;  // epilogue C/D mapping

    const unsigned short* Abase = Ag + (size_t)m0 * K;
    const unsigned short* Bbase = Bg + (size_t)ncol * 128 * K;
    // per-lane B fragment pointer: row (wn + jj*16 + fr), k-offset fq*8
    const unsigned short* Bp = Bbase + (size_t)(wn + fr) * K + fq * 8;

    // A staging: chunk-slot ids for the two issues; global k-chunk XOR-swizzled
    int c0 = tid, c1 = 256 + tid;
    size_t aoff0 = (size_t)(c0 >> 2) * K + 8 * ((c0 & 3) ^ ((c0 >> 3) & 3));
    size_t aoff1 = (size_t)(c1 >> 2) * K + 8 * ((c1 & 3) ^ ((c1 >> 3) & 3));

    // fragment LDS offsets (in shorts): slot(r, q) = 4r + (q ^ ((r&15)>>1 &3))
    int fswz = 8 * (fq ^ ((fr >> 1) & 3));

#define STAGEK(bi, kt_) do {                                                   \
        int _b  = (bi) * 4096;                                                 \
        int _k0 = (kt_) * 32;                                                  \
        GLD_LDS16(Abase + aoff0 + _k0, &smem[_b + c0 * 8]);                    \
        GLD_LDS16(Abase + aoff1 + _k0, &smem[_b + c1 * 8]);                    \
    } while (0)

#define BLOAD(dst, kt_) do {                                                   \
        _Pragma("unroll")                                                      \
        for (int _jj = 0; _jj < 4; ++_jj)                                      \
            dst[_jj] = *(const bf16x8*)&Bp[(size_t)_jj * 16 * K + (kt_) * 32]; \
    } while (0)

#define SBAR() do {                                                            \
        __builtin_amdgcn_sched_barrier(0);                                     \
        __builtin_amdgcn_s_barrier();                                          \
        __builtin_amdgcn_sched_barrier(0);                                     \
    } while (0)

#define GITER(kt_, BC, BN) do {                                                \
        int _base = ((kt_) % 3) * 4096;                                        \
        if ((kt_) + 1 < NT) { asm volatile("s_waitcnt vmcnt(2)" ::: "memory"); } \
        else                { asm volatile("s_waitcnt vmcnt(0)" ::: "memory"); } \
        SBAR();                                                                \
        if ((kt_) + 1 < NT) BLOAD(BN, (kt_) + 1);                              \
        __builtin_amdgcn_sched_barrier(0);                                     \
        if ((kt_) + 2 < NT) STAGEK(((kt_) + 2) % 3, (kt_) + 2);                \
        __builtin_amdgcn_sched_barrier(0);                                     \
        bf16x8 _af[4];                                                         \
        _Pragma("unroll")                                                      \
        for (int _i = 0; _i < 4; ++_i)                                         \
            _af[_i] = *(const bf16x8*)&smem[_base + (wm + _i * 16 + fr) * 32 + fswz]; \
        _Pragma("unroll")                                                      \
        for (int _i = 0; _i < 4; ++_i)                                         \
            _Pragma("unroll")                                                  \
            for (int _jj = 0; _jj < 4; ++_jj)                                  \
                acc[_i][_jj] = __builtin_amdgcn_mfma_f32_16x16x32_bf16(        \
                    _af[_i], BC[_jj], acc[_i][_jj], 0, 0, 0);                  \
    } while (0)

    f32x4 acc[4][4];
#pragma unroll
    for (int i = 0; i < 4; ++i)
#pragma unroll
        for (int jj = 0; jj < 4; ++jj)
            acc[i][jj] = (f32x4){0.f, 0.f, 0.f, 0.f};

    int NT = K >> 5;            // K/32: 10 or 20 (always even)
    bf16x8 bc[4], bn[4];

    // prologue: B(0) FIRST, then A(0), A(1) -- FIFO order feeds vmcnt(2) math
    BLOAD(bc, 0);
    __builtin_amdgcn_sched_barrier(0);
    STAGEK(0, 0);
    STAGEK(1, 1);
    __builtin_amdgcn_sched_barrier(0);

    for (int kt = 0; kt < NT; kt += 2) {
        GITER(kt,     bc, bn);
        GITER(kt + 1, bn, bc);
    }
    __syncthreads();   // epilogue reuses LDS; ensure all reads retired

    // ---- epilogue: bias + relu + bf16, LDS bounce for coalesced stores ----
#pragma unroll
    for (int ch = 0; ch < 2; ++ch) {
        if ((wn >> 6) == ch) {              // waves owning this 64-col half
#pragma unroll
            for (int jj = 0; jj < 4; ++jj) {
                int lc  = jj * 16 + colq;                  // 0..63
                int col = ncol * 128 + wn + jj * 16 + colq;
                float bv = (col < bias_n) ? bias[col] : 0.f;
#pragma unroll
                for (int i = 0; i < 4; ++i) {
                    int rbase = wm + i * 16 + rq;
#pragma unroll
                    for (int r = 0; r < 4; ++r) {
                        float v = fmaxf(acc[i][jj][r] + bv, 0.f);
                        smem[(rbase + r) * 64 + lc] = f2b(v);
                    }
                }
            }
        }
        __syncthreads();
        int cbase = ncol * 128 + ch * 64;
        if (cbase < store_cols) {
#pragma unroll
            for (int i = 0; i < 4; ++i) {
                int idx = i * 256 + tid;        // 0..1023 uint4 chunks
                int row = idx >> 3, c8 = idx & 7;
                *(uint4*)&C[(size_t)(m0 + row) * ldc + cbase + c8 * 8] =
                    *(uint4*)&smem[row * 64 + c8 * 8];
            }
        }
        __syncthreads();
    }
#undef GITER
#undef SBAR
#undef BLOAD
#undef STAGEK
}

// ---------------------------------------------------------------------------
// pool: g[gid] = sum of Hb rows (bf16, stride KP) with batch==gid (sorted)
// ---------------------------------------------------------------------------
__global__ __launch_bounds__(256) void k_pool(
    const unsigned short* __restrict__ H, const int* __restrict__ batch,
    float* __restrict__ g, int n)
{
    int gid = blockIdx.x;
    int lo = 0, hi = n;
    while (lo < hi) { int mid = (lo + hi) >> 1; if (batch[mid] < gid) lo = mid + 1; else hi = mid; }
    int start = lo;
    hi = n;
    while (lo < hi) { int mid = (lo + hi) >> 1; if (batch[mid] < gid + 1) lo = mid + 1; else hi = mid; }
    int end = lo;

    for (int f = threadIdx.x; f < NFEAT; f += blockDim.x) {
        float acc = 0.f;
        for (int v = start; v < end; ++v) acc += b2f(H[(size_t)v * KP + f]);
        g[(size_t)gid * NFEAT + f] = acc;
    }
}

// ---------------------------------------------------------------------------
// out = g @ Wfc + bfc   (2048x300 @ 300x300), fp32
// ---------------------------------------------------------------------------
__global__ __launch_bounds__(256) void k_final(
    const float* __restrict__ g, const float* __restrict__ Wfc,
    const float* __restrict__ bfc, float* __restrict__ out)
{
    int idx = blockIdx.x * blockDim.x + threadIdx.x;
    if (idx >= NGRAPH * NFEAT) return;
    int r = idx / NFEAT, c = idx % NFEAT;
    float acc = bfc[c];
    for (int k = 0; k < NFEAT; ++k)
        acc = fmaf(g[(size_t)r * NFEAT + k], Wfc[(size_t)k * NFEAT + c], acc);
    out[idx] = acc;
}

extern "C" void kernel_launch(void* const* d_in, const int* in_sizes, int n_in,
                              void* d_out, int out_size, void* d_ws, size_t ws_size,
                              hipStream_t stream)
{
    const float* x    = (const float*)d_in[0];
    const int*   ei   = (const int*)  d_in[1];
    const int*   ea   = (const int*)  d_in[2];
    const int*   batch= (const int*)  d_in[3];
    const float* emb1 = (const float*)d_in[4];
    const float* emb2 = (const float*)d_in[5];
    const float* W1   = (const float*)d_in[6];
    const float* b1   = (const float*)d_in[7];
    const float* W2   = (const float*)d_in[8];
    const float* b2   = (const float*)d_in[9];
    const float* Wfc  = (const float*)d_in[10];
    const float* bfc  = (const float*)d_in[11];
    float* out = (float*)d_out;

    int n = in_sizes[0] / NFEAT;   // 100000
    int E = in_sizes[1] / 2;       // 200000
    int MT   = (n + 127) / 128;    // 782
    int Mpad = MT * 128;           // 100096
    int MT8  = ((MT + 7) / 8) * 8; // 784 (XCD-swizzle padding)

    // ---- workspace layout ----
    char* p = (char*)d_ws;
    auto take = [&](size_t bytes) { char* r = p; p += (bytes + 255) & ~(size_t)255; return r; };
    unsigned short* T    = (unsigned short*)take((size_t)Mpad * N1P * 2); // 128.1 MB
    unsigned short* xb   = T;                                             // overlay (dead before T)
    unsigned short* Ab   = (unsigned short*)take((size_t)Mpad * KP * 2);  // 64.06 MB
    unsigned short* Hb   = (unsigned short*)take((size_t)Mpad * KP * 2);  // 64.06 MB
    unsigned short* Wt1  = (unsigned short*)take((size_t)N1P * KP * 2);
    unsigned short* Wt2  = (unsigned short*)take((size_t)N2P * N1P * 2);
    float*          embc = (float*)take((size_t)NTD * KP * 4);
    float*          g    = (float*)take((size_t)NGRAPH * NFEAT * 4);
    int*            deg  = (int*)take((size_t)n * 4);
    int*            offs = (int*)take((size_t)(n + 1) * 4);
    int*            curs = (int*)take((size_t)n * 4);
    int*            erec = (int*)take((size_t)E * 4);
    int*            bsum = (int*)take(256 * 4);

    dim3 blk(256);
    int chunkThreads = Mpad * (KP / 8);
    int chunkBlocks  = (chunkThreads + 255) / 256;
    int nb = (n + SCAN_B - 1) / SCAN_B;

    // ---- one-time prep (per call) ----
    k_cvtW<<<(N1P * KP + 255) / 256, blk, 0, stream>>>(W1, Wt1, NFEAT, 600, KP, N1P);
    k_cvtW<<<(N2P * N1P + 255) / 256, blk, 0, stream>>>(W2, Wt2, 600, NFEAT, N1P, N2P);
    k_embc<<<(NTD * KP + 255) / 256, blk, 0, stream>>>(emb1, emb2, embc);
    k_cvtX<<<chunkBlocks, blk, 0, stream>>>(x, xb, n, Mpad);

    // ---- CSR build ----
    k_zero <<<(n + 255) / 256, blk, 0, stream>>>(deg, n);
    k_deg  <<<(E + 255) / 256, blk, 0, stream>>>(ei, deg, E);
    k_scan1<<<nb, blk, 0, stream>>>(deg, offs, bsum, n);
    k_scan2<<<1, 64, 0, stream>>>(bsum, nb, offs);
    k_scan3<<<(n + 255) / 256, blk, 0, stream>>>(deg, offs, bsum, curs, n);
    k_fill <<<(E + 255) / 256, blk, 0, stream>>>(ei, ea, curs, erec, E);

    // ---- layer 1 ----
    k_aggr<<<chunkBlocks, blk, 0, stream>>>(xb, offs, erec, embc, Ab, n, Mpad);
    k_gemm<<<MT8 * (N1P / 128), blk, 0, stream>>>(Ab, Wt1, b1, 600, T, N1P, N1P, KP, N1P / 128, MT);
    k_gemm<<<MT8 * (N2P / 128), blk, 0, stream>>>(T, Wt2, b2, NFEAT, Hb, KP, KP, N1P, N2P / 128, MT);

    // ---- layer 2 ----
    k_aggr<<<chunkBlocks, blk, 0, stream>>>(Hb, offs, erec, embc, Ab, n, Mpad);
    k_gemm<<<MT8 * (N1P / 128), blk, 0, stream>>>(Ab, Wt1, b1, 600, T, N1P, N1P, KP, N1P / 128, MT);
    k_gemm<<<MT8 * (N2P / 128), blk, 0, stream>>>(T, Wt2, b2, NFEAT, Hb, KP, KP, N1P, N2P / 128, MT);

    // ---- pool + final ----
    k_pool <<<NGRAPH, blk, 0, stream>>>(Hb, batch, g, n);
    k_final<<<(NGRAPH * NFEAT + 255) / 256, blk, 0, stream>>>(g, Wfc, bfc, out);
}

// Round 5
// 728.440 us; speedup vs baseline: 1.1912x; 1.1912x over previous
//
#include <hip/hip_runtime.h>
#include <hip/hip_bf16.h>

#define NFEAT 300
#define KP 320           // padded feature stride (bf16 rows)
#define NGRAPH 2048
#define N1P 640          // padded N for GEMM1 (600 -> 640)
#define N2P 384          // padded N for GEMM2 (300 -> 384)
#define NTD 18           // bond_type(6) * bond_dir(3)
#define SCAN_B 2048      // elements per scan block (256 thr * 8)

typedef __bf16 bf16x8 __attribute__((ext_vector_type(8)));
typedef float  f32x4  __attribute__((ext_vector_type(4)));
typedef unsigned short u16x8 __attribute__((ext_vector_type(8)));

__device__ __forceinline__ unsigned short f2b(float v) {
    union { float f; unsigned u; } x; x.f = v;
    unsigned r = x.u + 0x7fff + ((x.u >> 16) & 1);   // RNE
    return (unsigned short)(r >> 16);
}
__device__ __forceinline__ float b2f(unsigned short u) {
    union { unsigned u; float f; } x; x.u = ((unsigned)u) << 16;
    return x.f;
}

#define GLD_LDS16(g, l)                                                        \
    __builtin_amdgcn_global_load_lds(                                          \
        (const __attribute__((address_space(1))) void*)(g),                    \
        (__attribute__((address_space(3))) void*)(l), 16, 0, 0)

// ---------------------------------------------------------------------------
// embc[td][c] = emb1[td/3][c] + emb2[td%3][c]  (fp32, [18 x 320], pad cols 0)
// ---------------------------------------------------------------------------
__global__ __launch_bounds__(256) void k_embc(
    const float* __restrict__ emb1, const float* __restrict__ emb2,
    float* __restrict__ embc)
{
    int t = blockIdx.x * blockDim.x + threadIdx.x;
    if (t >= NTD * KP) return;
    int td = t / KP, c = t % KP;
    int t1 = td / 3, d = td % 3;
    embc[t] = (c < NFEAT) ? emb1[t1 * NFEAT + c] + emb2[d * NFEAT + c] : 0.f;
}

// ---------------------------------------------------------------------------
// CSR build: deg -> exclusive-scan offsets -> cursor fill, packed records
// ---------------------------------------------------------------------------
__global__ __launch_bounds__(256) void k_zero(int* __restrict__ p, int n)
{
    int i = blockIdx.x * blockDim.x + threadIdx.x;
    if (i < n) p[i] = 0;
}

__global__ __launch_bounds__(256) void k_deg(
    const int* __restrict__ ei, int* __restrict__ deg, int E)
{
    int e = blockIdx.x * blockDim.x + threadIdx.x;
    if (e >= E) return;
    atomicAdd(&deg[ei[E + e]], 1);
}

__global__ __launch_bounds__(256) void k_scan1(
    const int* __restrict__ deg, int* __restrict__ offsets,
    int* __restrict__ bsum, int n)
{
    __shared__ int sh[256];
    int tid = threadIdx.x;
    int base = blockIdx.x * SCAN_B + tid * 8;
    int v[8], run = 0;
#pragma unroll
    for (int j = 0; j < 8; ++j) {
        int i = base + j;
        v[j] = (i < n) ? deg[i] : 0;
        run += v[j];
        v[j] = run;
    }
    sh[tid] = run;
    __syncthreads();
    for (int off = 1; off < 256; off <<= 1) {
        int t = (tid >= off) ? sh[tid - off] : 0;
        __syncthreads();
        sh[tid] += t;
        __syncthreads();
    }
    int excl = sh[tid] - run;
#pragma unroll
    for (int j = 0; j < 8; ++j) {
        int i = base + j;
        if (i < n) offsets[i + 1] = excl + v[j];
    }
    if (tid == 0) bsum[blockIdx.x] = sh[255];
}

__global__ void k_scan2(int* __restrict__ bsum, int nb, int* __restrict__ offsets)
{
    if (threadIdx.x == 0 && blockIdx.x == 0) {
        int run = 0;
        for (int b = 0; b < nb; ++b) { int t = bsum[b]; bsum[b] = run; run += t; }
        offsets[0] = 0;
    }
}

__global__ __launch_bounds__(256) void k_scan3(
    const int* __restrict__ deg, int* __restrict__ offsets,
    const int* __restrict__ bsum, int* __restrict__ cursor, int n)
{
    int i = blockIdx.x * blockDim.x + threadIdx.x;
    if (i >= n) return;
    int fin = offsets[i + 1] + bsum[i / SCAN_B];
    offsets[i + 1] = fin;
    cursor[i] = fin - deg[i];
}

__global__ __launch_bounds__(256) void k_fill(
    const int* __restrict__ ei, const int* __restrict__ ea,
    int* __restrict__ cursor, int* __restrict__ edgerec, int E)
{
    int e = blockIdx.x * blockDim.x + threadIdx.x;
    if (e >= E) return;
    int dst = ei[E + e];
    int pos = atomicAdd(&cursor[dst], 1);
    int src = ei[e];
    int td  = ea[2 * e] * 3 + ea[2 * e + 1];
    edgerec[pos] = src | (td << 20);
}

// ---------------------------------------------------------------------------
// Layer-1 aggregation reading fp32 x DIRECTLY (replaces k_cvtX + bf16 aggr):
// Ab[v] = bf16( x[v] + embc[0] + sum_{e: dst=v} ( x[src_e] + embc[td_e] ) )
// x rows are 1200 B (16-aligned); full 8-col chunks use 2x float4.
// ---------------------------------------------------------------------------
__global__ __launch_bounds__(256) void k_aggr_f32(
    const float* __restrict__ x,
    const int* __restrict__ offsets, const int* __restrict__ edgerec,
    const float* __restrict__ embc,
    unsigned short* __restrict__ Ab, int n, int Mpad)
{
    int idx = blockIdx.x * blockDim.x + threadIdx.x;
    if (idx >= Mpad * (KP / 8)) return;
    int v = idx / (KP / 8), c0 = (idx % (KP / 8)) * 8;
    unsigned short* outp = &Ab[(size_t)v * KP + c0];
    if (v >= n || c0 >= 304) {          // pad rows, or all-pad chunks (304,312)
        *(uint4*)outp = make_uint4(0, 0, 0, 0);
        return;
    }
    float acc[8];
    const float* e0 = embc + c0;
    int beg = offsets[v], end = offsets[v + 1];

    if (c0 + 8 <= NFEAT) {              // full chunk: vectorized float4 x2
        const float* xr = &x[(size_t)v * NFEAT + c0];
        float4 a0 = *(const float4*)xr;
        float4 a1 = *(const float4*)(xr + 4);
        acc[0] = a0.x + e0[0]; acc[1] = a0.y + e0[1];
        acc[2] = a0.z + e0[2]; acc[3] = a0.w + e0[3];
        acc[4] = a1.x + e0[4]; acc[5] = a1.y + e0[5];
        acc[6] = a1.z + e0[6]; acc[7] = a1.w + e0[7];
        for (int e = beg; e < end; ++e) {
            int rec = edgerec[e];
            int src = rec & 0xFFFFF;
            int td  = rec >> 20;
            const float* xs = &x[(size_t)src * NFEAT + c0];
            float4 s0 = *(const float4*)xs;
            float4 s1 = *(const float4*)(xs + 4);
            const float* ee = embc + td * KP + c0;
            acc[0] += s0.x + ee[0]; acc[1] += s0.y + ee[1];
            acc[2] += s0.z + ee[2]; acc[3] += s0.w + ee[3];
            acc[4] += s1.x + ee[4]; acc[5] += s1.y + ee[5];
            acc[6] += s1.z + ee[6]; acc[7] += s1.w + ee[7];
        }
    } else {                            // partial chunk (c0 = 296): guarded
#pragma unroll
        for (int j = 0; j < 8; ++j) {
            int col = c0 + j;
            acc[j] = ((col < NFEAT) ? x[(size_t)v * NFEAT + col] : 0.f) + e0[j];
        }
        for (int e = beg; e < end; ++e) {
            int rec = edgerec[e];
            int src = rec & 0xFFFFF;
            int td  = rec >> 20;
            const float* ee = embc + td * KP + c0;
#pragma unroll
            for (int j = 0; j < 8; ++j) {
                int col = c0 + j;
                acc[j] += ((col < NFEAT) ? x[(size_t)src * NFEAT + col] : 0.f) + ee[j];
            }
        }
    }
    unsigned short o[8];
#pragma unroll
    for (int j = 0; j < 8; ++j) o[j] = f2b(acc[j]);
    *(uint4*)outp = *(uint4*)o;
}

// ---------------------------------------------------------------------------
// Gather-side aggregation (bf16 h, layer 2):
// Ab[v] = bf16( h[v] + embc[0] + sum_{e: dst=v} ( h[src_e] + embc[td_e] ) )
// ---------------------------------------------------------------------------
__global__ __launch_bounds__(256) void k_aggr(
    const unsigned short* __restrict__ h,
    const int* __restrict__ offsets, const int* __restrict__ edgerec,
    const float* __restrict__ embc,
    unsigned short* __restrict__ Ab, int n, int Mpad)
{
    int idx = blockIdx.x * blockDim.x + threadIdx.x;
    if (idx >= Mpad * (KP / 8)) return;
    int v = idx / (KP / 8), c0 = (idx % (KP / 8)) * 8;
    unsigned short* outp = &Ab[(size_t)v * KP + c0];
    if (v >= n) {
        *(uint4*)outp = make_uint4(0, 0, 0, 0);
        return;
    }
    float acc[8];
    u16x8 hv = *(const u16x8*)&h[(size_t)v * KP + c0];
    const float* e0 = embc + c0;
#pragma unroll
    for (int j = 0; j < 8; ++j) acc[j] = b2f(hv[j]) + e0[j];

    int beg = offsets[v], end = offsets[v + 1];
    for (int e = beg; e < end; ++e) {
        int rec = edgerec[e];
        int src = rec & 0xFFFFF;
        int td  = rec >> 20;
        u16x8 hs = *(const u16x8*)&h[(size_t)src * KP + c0];
        const float* ee = embc + td * KP + c0;
#pragma unroll
        for (int j = 0; j < 8; ++j) acc[j] += b2f(hs[j]) + ee[j];
    }
    unsigned short o[8];
#pragma unroll
    for (int j = 0; j < 8; ++j) o[j] = f2b(acc[j]);
    *(uint4*)outp = *(uint4*)o;
}

// ---------------------------------------------------------------------------
// Wt[n*Kpad + k] = bf16(W[k*cols + n]) if in range else 0
// ---------------------------------------------------------------------------
__global__ __launch_bounds__(256) void k_cvtW(
    const float* __restrict__ W, unsigned short* __restrict__ Wt,
    int rows, int cols, int Kpad, int Npad)
{
    int t = blockIdx.x * blockDim.x + threadIdx.x;
    if (t >= Npad * Kpad) return;
    int nn = t / Kpad, k = t % Kpad;
    float v = (k < rows && nn < cols) ? W[(size_t)k * cols + nn] : 0.f;
    Wt[t] = f2b(v);
}

// ---------------------------------------------------------------------------
// bf16 MFMA GEMM, grid-parallel + XCD-swizzled + XOR-swizzled LDS.
//
// v4 structure (PROVEN 77 us / 26.5% MfmaUtil -- v5's B-bypass regressed
// to 124 us because global L1/L2 vector loads are a slower path per byte
// than LDS ds_read, and B retirement landed on the per-iter critical
// path with ~1 iter of latency slack).
//
// T3+T4 counted-vmcnt pipeline: triple-buffered LDS (3 x 16 KB), depth-2
// prefetch, ONE raw s_barrier per K-step with counted s_waitcnt vmcnt(4)
// (vmcnt(0) only on the last iteration) so up to 8 staging loads stay in
// flight across barriers.
//
// Hazard audit:
//  - wait vmcnt(4) BEFORE the barrier: each wave waits for its own
//    tile-kt loads (the oldest 4 of <=8 outstanding); after the
//    barrier, every wave's tile-kt loads have landed -> LDS complete.
//  - STAGE is issued AFTER the barrier: its target buffer (kt+2)%3 ==
//    (kt-1)%3 was last read in iter kt-1; those ds_reads retired
//    (compiler lgkmcnt before MFMA use) before each wave reached this
//    barrier, so no write-before-read race.
//  - sched_barrier(0) sandwiches s_barrier (raw s_barrier is not a
//    compiler fence); asm waits carry "memory" clobbers so ds_reads /
//    STAGE issues cannot be hoisted across them.
//  - __syncthreads() after the loop: epilogue overwrites buffer 0,
//    which for NT=10 is the buffer read in the final iteration.
//
// Staging lane L fetches row (L>>2), k-chunk ((L&3) ^ ((L>>3)&3)) -- the 4
// lanes of a row cover the same contiguous 64B (coalesced, 16 lines/wave),
// while chunk (r,c) lands at LDS slot 4r + (c ^ ((r>>1)&3)). Fragment
// ds_read_b128 phases then hit bank-group positions 0,4,1,5,2,6,3,7 -- a
// perfect minimum sweep (2-way aliasing only, which is free).
// Epilogue bounces accumulators through LDS for coalesced uint4 stores.
// C = relu(A @ Bt^T + bias). A [Mpad x K] rm bf16, Bt [N x K] rm bf16.
// ---------------------------------------------------------------------------
__global__ __launch_bounds__(256) void k_gemm(
    const unsigned short* __restrict__ Ag, const unsigned short* __restrict__ Bg,
    const float* __restrict__ bias, int bias_n,
    unsigned short* __restrict__ C, int ldc, int store_cols,
    int K, int npass, int MT)
{
    __shared__ unsigned short smem[24576];  // 48 KB: 3 buffers of (sA 4K | sB 4K shorts)

    int tid  = threadIdx.x;
    int lane = tid & 63, wave = tid >> 6;

    // XCD-swizzle: same panel -> same XCD for all npass column tiles
    int l    = blockIdx.x;
    int xcd  = l & 7;
    int j    = l >> 3;
    int ncol = j % npass;
    int panel= (j / npass) * 8 + xcd;
    if (panel >= MT) return;
    int m0 = panel * 128;

    int wm = (wave >> 1) * 64, wn = (wave & 1) * 64;
    int fr = lane & 15, fq = lane >> 4;          // fragment row / k-chunk
    int colq = lane & 15, rq = (lane >> 4) * 4;  // epilogue C/D mapping

    const unsigned short* Abase = Ag + (size_t)m0 * K;
    const unsigned short* Bbase = Bg + (size_t)ncol * 128 * K;

    // staging: chunk-slot ids for the two issues; global k-chunk is XOR-swizzled
    int c0 = tid, c1 = 256 + tid;
    size_t aoff0 = (size_t)(c0 >> 2) * K + 8 * ((c0 & 3) ^ ((c0 >> 3) & 3));
    size_t aoff1 = (size_t)(c1 >> 2) * K + 8 * ((c1 & 3) ^ ((c1 >> 3) & 3));

    // fragment LDS offsets (in shorts): slot(r, q) = 4r + (q ^ ((r&15)>>1 &3))
    int fswz = 8 * (fq ^ ((fr >> 1) & 3));

#define STAGEK(bi, kt_) do {                                                   \
        int _b  = (bi) * 8192;                                                 \
        int _k0 = (kt_) * 32;                                                  \
        GLD_LDS16(Abase + aoff0 + _k0, &smem[_b + c0 * 8]);                    \
        GLD_LDS16(Abase + aoff1 + _k0, &smem[_b + c1 * 8]);                    \
        GLD_LDS16(Bbase + aoff0 + _k0, &smem[_b + 4096 + c0 * 8]);             \
        GLD_LDS16(Bbase + aoff1 + _k0, &smem[_b + 4096 + c1 * 8]);             \
    } while (0)

#define SBAR() do {                                                            \
        __builtin_amdgcn_sched_barrier(0);                                     \
        __builtin_amdgcn_s_barrier();                                          \
        __builtin_amdgcn_sched_barrier(0);                                     \
    } while (0)

    f32x4 acc[4][4];
#pragma unroll
    for (int i = 0; i < 4; ++i)
#pragma unroll
        for (int jj = 0; jj < 4; ++jj)
            acc[i][jj] = (f32x4){0.f, 0.f, 0.f, 0.f};

    int NT = K >> 5;            // K/32 (10 or 20), always >= 2
    STAGEK(0, 0);               // prologue: depth-2 pipeline fill
    STAGEK(1, 1);

    for (int kt = 0; kt < NT; ++kt) {
        int base = (kt % 3) * 8192;

        // tile kt is the oldest 4 of <=8 outstanding loads
        if (kt + 1 < NT) {
            asm volatile("s_waitcnt vmcnt(4)" ::: "memory");
        } else {
            asm volatile("s_waitcnt vmcnt(0)" ::: "memory");
        }
        SBAR();   // tile kt visible to all; buffer (kt+2)%3 free for reuse

        if (kt + 2 < NT) STAGEK((kt + 2) % 3, kt + 2);

        bf16x8 af[4], bfv[4];
#pragma unroll
        for (int i = 0; i < 4; ++i) {
            af[i]  = *(const bf16x8*)&smem[base + (wm + i * 16 + fr) * 32 + fswz];
            bfv[i] = *(const bf16x8*)&smem[base + 4096 + (wn + i * 16 + fr) * 32 + fswz];
        }
#pragma unroll
        for (int i = 0; i < 4; ++i)
#pragma unroll
            for (int jj = 0; jj < 4; ++jj)
                acc[i][jj] = __builtin_amdgcn_mfma_f32_16x16x32_bf16(
                    af[i], bfv[jj], acc[i][jj], 0, 0, 0);
    }
    __syncthreads();   // epilogue reuses buffer 0; ensure all reads retired

    // ---- epilogue: bias + relu + bf16, LDS bounce for coalesced stores ----
#pragma unroll
    for (int ch = 0; ch < 2; ++ch) {
        if ((wn >> 6) == ch) {              // waves owning this 64-col half
#pragma unroll
            for (int jj = 0; jj < 4; ++jj) {
                int lc  = jj * 16 + colq;                  // 0..63
                int col = ncol * 128 + wn + jj * 16 + colq;
                float bv = (col < bias_n) ? bias[col] : 0.f;
#pragma unroll
                for (int i = 0; i < 4; ++i) {
                    int rbase = wm + i * 16 + rq;
#pragma unroll
                    for (int r = 0; r < 4; ++r) {
                        float v = fmaxf(acc[i][jj][r] + bv, 0.f);
                        smem[(rbase + r) * 64 + lc] = f2b(v);
                    }
                }
            }
        }
        __syncthreads();
        int cbase = ncol * 128 + ch * 64;
        if (cbase < store_cols) {
#pragma unroll
            for (int i = 0; i < 4; ++i) {
                int idx = i * 256 + tid;        // 0..1023 uint4 chunks
                int row = idx >> 3, c8 = idx & 7;
                *(uint4*)&C[(size_t)(m0 + row) * ldc + cbase + c8 * 8] =
                    *(uint4*)&smem[row * 64 + c8 * 8];
            }
        }
        __syncthreads();
    }
#undef STAGEK
#undef SBAR
}

// ---------------------------------------------------------------------------
// pool: g[gid] = sum of Hb rows (bf16, stride KP) with batch==gid (sorted)
// ---------------------------------------------------------------------------
__global__ __launch_bounds__(256) void k_pool(
    const unsigned short* __restrict__ H, const int* __restrict__ batch,
    float* __restrict__ g, int n)
{
    int gid = blockIdx.x;
    int lo = 0, hi = n;
    while (lo < hi) { int mid = (lo + hi) >> 1; if (batch[mid] < gid) lo = mid + 1; else hi = mid; }
    int start = lo;
    hi = n;
    while (lo < hi) { int mid = (lo + hi) >> 1; if (batch[mid] < gid + 1) lo = mid + 1; else hi = mid; }
    int end = lo;

    for (int f = threadIdx.x; f < NFEAT; f += blockDim.x) {
        float acc = 0.f;
        for (int v = start; v < end; ++v) acc += b2f(H[(size_t)v * KP + f]);
        g[(size_t)gid * NFEAT + f] = acc;
    }
}

// ---------------------------------------------------------------------------
// out = g @ Wfc + bfc   (2048x300 @ 300x300), fp32
// ---------------------------------------------------------------------------
__global__ __launch_bounds__(256) void k_final(
    const float* __restrict__ g, const float* __restrict__ Wfc,
    const float* __restrict__ bfc, float* __restrict__ out)
{
    int idx = blockIdx.x * blockDim.x + threadIdx.x;
    if (idx >= NGRAPH * NFEAT) return;
    int r = idx / NFEAT, c = idx % NFEAT;
    float acc = bfc[c];
    for (int k = 0; k < NFEAT; ++k)
        acc = fmaf(g[(size_t)r * NFEAT + k], Wfc[(size_t)k * NFEAT + c], acc);
    out[idx] = acc;
}

extern "C" void kernel_launch(void* const* d_in, const int* in_sizes, int n_in,
                              void* d_out, int out_size, void* d_ws, size_t ws_size,
                              hipStream_t stream)
{
    const float* x    = (const float*)d_in[0];
    const int*   ei   = (const int*)  d_in[1];
    const int*   ea   = (const int*)  d_in[2];
    const int*   batch= (const int*)  d_in[3];
    const float* emb1 = (const float*)d_in[4];
    const float* emb2 = (const float*)d_in[5];
    const float* W1   = (const float*)d_in[6];
    const float* b1   = (const float*)d_in[7];
    const float* W2   = (const float*)d_in[8];
    const float* b2   = (const float*)d_in[9];
    const float* Wfc  = (const float*)d_in[10];
    const float* bfc  = (const float*)d_in[11];
    float* out = (float*)d_out;

    int n = in_sizes[0] / NFEAT;   // 100000
    int E = in_sizes[1] / 2;       // 200000
    int MT   = (n + 127) / 128;    // 782
    int Mpad = MT * 128;           // 100096
    int MT8  = ((MT + 7) / 8) * 8; // 784 (XCD-swizzle padding)

    // ---- workspace layout ----
    char* p = (char*)d_ws;
    auto take = [&](size_t bytes) { char* r = p; p += (bytes + 255) & ~(size_t)255; return r; };
    unsigned short* T    = (unsigned short*)take((size_t)Mpad * N1P * 2); // 128.1 MB
    unsigned short* Ab   = (unsigned short*)take((size_t)Mpad * KP * 2);  // 64.06 MB
    unsigned short* Hb   = (unsigned short*)take((size_t)Mpad * KP * 2);  // 64.06 MB
    unsigned short* Wt1  = (unsigned short*)take((size_t)N1P * KP * 2);
    unsigned short* Wt2  = (unsigned short*)take((size_t)N2P * N1P * 2);
    float*          embc = (float*)take((size_t)NTD * KP * 4);
    float*          g    = (float*)take((size_t)NGRAPH * NFEAT * 4);
    int*            deg  = (int*)take((size_t)n * 4);
    int*            offs = (int*)take((size_t)(n + 1) * 4);
    int*            curs = (int*)take((size_t)n * 4);
    int*            erec = (int*)take((size_t)E * 4);
    int*            bsum = (int*)take(256 * 4);

    dim3 blk(256);
    int chunkThreads = Mpad * (KP / 8);
    int chunkBlocks  = (chunkThreads + 255) / 256;
    int nb = (n + SCAN_B - 1) / SCAN_B;

    // ---- one-time prep (per call) ----
    k_cvtW<<<(N1P * KP + 255) / 256, blk, 0, stream>>>(W1, Wt1, NFEAT, 600, KP, N1P);
    k_cvtW<<<(N2P * N1P + 255) / 256, blk, 0, stream>>>(W2, Wt2, 600, NFEAT, N1P, N2P);
    k_embc<<<(NTD * KP + 255) / 256, blk, 0, stream>>>(emb1, emb2, embc);

    // ---- CSR build ----
    k_zero <<<(n + 255) / 256, blk, 0, stream>>>(deg, n);
    k_deg  <<<(E + 255) / 256, blk, 0, stream>>>(ei, deg, E);
    k_scan1<<<nb, blk, 0, stream>>>(deg, offs, bsum, n);
    k_scan2<<<1, 64, 0, stream>>>(bsum, nb, offs);
    k_scan3<<<(n + 255) / 256, blk, 0, stream>>>(deg, offs, bsum, curs, n);
    k_fill <<<(E + 255) / 256, blk, 0, stream>>>(ei, ea, curs, erec, E);

    // ---- layer 1 (aggr reads fp32 x directly; cvtX pass eliminated) ----
    k_aggr_f32<<<chunkBlocks, blk, 0, stream>>>(x, offs, erec, embc, Ab, n, Mpad);
    k_gemm<<<MT8 * (N1P / 128), blk, 0, stream>>>(Ab, Wt1, b1, 600, T, N1P, N1P, KP, N1P / 128, MT);
    k_gemm<<<MT8 * (N2P / 128), blk, 0, stream>>>(T, Wt2, b2, NFEAT, Hb, KP, KP, N1P, N2P / 128, MT);

    // ---- layer 2 ----
    k_aggr<<<chunkBlocks, blk, 0, stream>>>(Hb, offs, erec, embc, Ab, n, Mpad);
    k_gemm<<<MT8 * (N1P / 128), blk, 0, stream>>>(Ab, Wt1, b1, 600, T, N1P, N1P, KP, N1P / 128, MT);
    k_gemm<<<MT8 * (N2P / 128), blk, 0, stream>>>(T, Wt2, b2, NFEAT, Hb, KP, KP, N1P, N2P / 128, MT);

    // ---- pool + final ----
    k_pool <<<NGRAPH, blk, 0, stream>>>(Hb, batch, g, n);
    k_final<<<(NGRAPH * NFEAT + 255) / 256, blk, 0, stream>>>(g, Wfc, bfc, out);
}

// Round 6
// 666.744 us; speedup vs baseline: 1.3014x; 1.0925x over previous
//
#include <hip/hip_runtime.h>
#include <hip/hip_bf16.h>

#define NFEAT 300
#define KP 320           // padded feature stride (bf16 rows)
#define NGRAPH 2048
#define N1P 640          // padded N for GEMM1 (600 -> 640)
#define N2P 384          // padded N for GEMM2 (300 -> 384)
#define NTD 18           // bond_type(6) * bond_dir(3)
#define SCAN_B 2048      // elements per scan block (256 thr * 8)

typedef __bf16 bf16x8 __attribute__((ext_vector_type(8)));
typedef float  f32x4  __attribute__((ext_vector_type(4)));
typedef unsigned short u16x8 __attribute__((ext_vector_type(8)));

__device__ __forceinline__ unsigned short f2b(float v) {
    union { float f; unsigned u; } x; x.f = v;
    unsigned r = x.u + 0x7fff + ((x.u >> 16) & 1);   // RNE
    return (unsigned short)(r >> 16);
}
__device__ __forceinline__ float b2f(unsigned short u) {
    union { unsigned u; float f; } x; x.u = ((unsigned)u) << 16;
    return x.f;
}

#define GLD_LDS16(g, l)                                                        \
    __builtin_amdgcn_global_load_lds(                                          \
        (const __attribute__((address_space(1))) void*)(g),                    \
        (__attribute__((address_space(3))) void*)(l), 16, 0, 0)

// ---------------------------------------------------------------------------
// embc[td][c] = emb1[td/3][c] + emb2[td%3][c]  (fp32, [18 x 320], pad cols 0)
// ---------------------------------------------------------------------------
__global__ __launch_bounds__(256) void k_embc(
    const float* __restrict__ emb1, const float* __restrict__ emb2,
    float* __restrict__ embc)
{
    int t = blockIdx.x * blockDim.x + threadIdx.x;
    if (t >= NTD * KP) return;
    int td = t / KP, c = t % KP;
    int t1 = td / 3, d = td % 3;
    embc[t] = (c < NFEAT) ? emb1[t1 * NFEAT + c] + emb2[d * NFEAT + c] : 0.f;
}

// ---------------------------------------------------------------------------
// x fp32 [n x 300] -> xb bf16 [Mpad x 320] (pads zero)
// Restored (R5 lesson): the scattered edge-gather must read the COMPACT bf16
// form; fp32 direct gather doubled scatter-limited traffic (113 us vs ~95).
// ---------------------------------------------------------------------------
__global__ __launch_bounds__(256) void k_cvtX(
    const float* __restrict__ x, unsigned short* __restrict__ xb, int n, int Mpad)
{
    int idx = blockIdx.x * blockDim.x + threadIdx.x;
    if (idx >= Mpad * (KP / 8)) return;
    int row = idx / (KP / 8), c0 = (idx % (KP / 8)) * 8;
    unsigned short o[8];
#pragma unroll
    for (int j = 0; j < 8; ++j) {
        int col = c0 + j;
        float v = (row < n && col < NFEAT) ? x[(size_t)row * NFEAT + col] : 0.f;
        o[j] = f2b(v);
    }
    *(uint4*)&xb[(size_t)row * KP + c0] = *(uint4*)o;
}

// ---------------------------------------------------------------------------
// CSR build: deg -> exclusive-scan offsets -> cursor fill, packed records
// ---------------------------------------------------------------------------
__global__ __launch_bounds__(256) void k_zero(int* __restrict__ p, int n)
{
    int i = blockIdx.x * blockDim.x + threadIdx.x;
    if (i < n) p[i] = 0;
}

__global__ __launch_bounds__(256) void k_deg(
    const int* __restrict__ ei, int* __restrict__ deg, int E)
{
    int e = blockIdx.x * blockDim.x + threadIdx.x;
    if (e >= E) return;
    atomicAdd(&deg[ei[E + e]], 1);
}

__global__ __launch_bounds__(256) void k_scan1(
    const int* __restrict__ deg, int* __restrict__ offsets,
    int* __restrict__ bsum, int n)
{
    __shared__ int sh[256];
    int tid = threadIdx.x;
    int base = blockIdx.x * SCAN_B + tid * 8;
    int v[8], run = 0;
#pragma unroll
    for (int j = 0; j < 8; ++j) {
        int i = base + j;
        v[j] = (i < n) ? deg[i] : 0;
        run += v[j];
        v[j] = run;
    }
    sh[tid] = run;
    __syncthreads();
    for (int off = 1; off < 256; off <<= 1) {
        int t = (tid >= off) ? sh[tid - off] : 0;
        __syncthreads();
        sh[tid] += t;
        __syncthreads();
    }
    int excl = sh[tid] - run;
#pragma unroll
    for (int j = 0; j < 8; ++j) {
        int i = base + j;
        if (i < n) offsets[i + 1] = excl + v[j];
    }
    if (tid == 0) bsum[blockIdx.x] = sh[255];
}

__global__ void k_scan2(int* __restrict__ bsum, int nb, int* __restrict__ offsets)
{
    if (threadIdx.x == 0 && blockIdx.x == 0) {
        int run = 0;
        for (int b = 0; b < nb; ++b) { int t = bsum[b]; bsum[b] = run; run += t; }
        offsets[0] = 0;
    }
}

__global__ __launch_bounds__(256) void k_scan3(
    const int* __restrict__ deg, int* __restrict__ offsets,
    const int* __restrict__ bsum, int* __restrict__ cursor, int n)
{
    int i = blockIdx.x * blockDim.x + threadIdx.x;
    if (i >= n) return;
    int fin = offsets[i + 1] + bsum[i / SCAN_B];
    offsets[i + 1] = fin;
    cursor[i] = fin - deg[i];
}

__global__ __launch_bounds__(256) void k_fill(
    const int* __restrict__ ei, const int* __restrict__ ea,
    int* __restrict__ cursor, int* __restrict__ edgerec, int E)
{
    int e = blockIdx.x * blockDim.x + threadIdx.x;
    if (e >= E) return;
    int dst = ei[E + e];
    int pos = atomicAdd(&cursor[dst], 1);
    int src = ei[e];
    int td  = ea[2 * e] * 3 + ea[2 * e + 1];
    edgerec[pos] = src | (td << 20);
}

// ---------------------------------------------------------------------------
// Gather-side aggregation:
// Ab[v] = bf16( h[v] + embc[0] + sum_{e: dst=v} ( h[src_e] + embc[td_e] ) )
// ---------------------------------------------------------------------------
__global__ __launch_bounds__(256) void k_aggr(
    const unsigned short* __restrict__ h,
    const int* __restrict__ offsets, const int* __restrict__ edgerec,
    const float* __restrict__ embc,
    unsigned short* __restrict__ Ab, int n, int Mpad)
{
    int idx = blockIdx.x * blockDim.x + threadIdx.x;
    if (idx >= Mpad * (KP / 8)) return;
    int v = idx / (KP / 8), c0 = (idx % (KP / 8)) * 8;
    unsigned short* outp = &Ab[(size_t)v * KP + c0];
    if (v >= n) {
        *(uint4*)outp = make_uint4(0, 0, 0, 0);
        return;
    }
    float acc[8];
    u16x8 hv = *(const u16x8*)&h[(size_t)v * KP + c0];
    const float* e0 = embc + c0;
#pragma unroll
    for (int j = 0; j < 8; ++j) acc[j] = b2f(hv[j]) + e0[j];

    int beg = offsets[v], end = offsets[v + 1];
    for (int e = beg; e < end; ++e) {
        int rec = edgerec[e];
        int src = rec & 0xFFFFF;
        int td  = rec >> 20;
        u16x8 hs = *(const u16x8*)&h[(size_t)src * KP + c0];
        const float* ee = embc + td * KP + c0;
#pragma unroll
        for (int j = 0; j < 8; ++j) acc[j] += b2f(hs[j]) + ee[j];
    }
    unsigned short o[8];
#pragma unroll
    for (int j = 0; j < 8; ++j) o[j] = f2b(acc[j]);
    *(uint4*)outp = *(uint4*)o;
}

// ---------------------------------------------------------------------------
// Wt[n*Kpad + k] = bf16(W[k*cols + n]) if in range else 0
// ---------------------------------------------------------------------------
__global__ __launch_bounds__(256) void k_cvtW(
    const float* __restrict__ W, unsigned short* __restrict__ Wt,
    int rows, int cols, int Kpad, int Npad)
{
    int t = blockIdx.x * blockDim.x + threadIdx.x;
    if (t >= Npad * Kpad) return;
    int nn = t / Kpad, k = t % Kpad;
    float v = (k < rows && nn < cols) ? W[(size_t)k * cols + nn] : 0.f;
    Wt[t] = f2b(v);
}

// ---------------------------------------------------------------------------
// bf16 MFMA GEMM -- EXACT v4 structure (proven 77 us / 26.5% MfmaUtil).
//
// Model: per block K-step the LDS port moves 48 KB (16 stage + 32 read,
// 2x read duplication from the 2x2 wave grid) = 375 cyc at 128 B/cyc;
// with 3 blocks/CU the port is ~78% busy -> structural MfmaUtil ceiling
// ~34%; measured 26.5%. v5 (B via global) proved the alternate data path
// is worse. Further gains need a wave-geometry restructure, not tweaks.
//
// T3+T4 counted-vmcnt pipeline: triple-buffered LDS (3 x 16 KB), depth-2
// prefetch, ONE raw s_barrier per K-step with counted s_waitcnt vmcnt(4)
// (vmcnt(0) only on the last iteration) so up to 8 staging loads stay in
// flight across barriers. Hazard audit in R3 notes: wait-before-barrier
// covers tile kt; STAGE-after-barrier covers buffer reuse; sched_barrier
// sandwiches every s_barrier; trailing __syncthreads covers epilogue.
//
// Staging lane L fetches row (L>>2), k-chunk ((L&3) ^ ((L>>3)&3)); chunk
// (r,c) lands at LDS slot 4r + (c ^ ((r>>1)&3)); fragment ds_read_b128
// phases sweep bank groups conflict-free (2-way only, free).
// Epilogue bounces accumulators through LDS for coalesced uint4 stores.
// C = relu(A @ Bt^T + bias). A [Mpad x K] rm bf16, Bt [N x K] rm bf16.
// ---------------------------------------------------------------------------
__global__ __launch_bounds__(256) void k_gemm(
    const unsigned short* __restrict__ Ag, const unsigned short* __restrict__ Bg,
    const float* __restrict__ bias, int bias_n,
    unsigned short* __restrict__ C, int ldc, int store_cols,
    int K, int npass, int MT)
{
    __shared__ unsigned short smem[24576];  // 48 KB: 3 buffers of (sA 4K | sB 4K shorts)

    int tid  = threadIdx.x;
    int lane = tid & 63, wave = tid >> 6;

    // XCD-swizzle: same panel -> same XCD for all npass column tiles
    int l    = blockIdx.x;
    int xcd  = l & 7;
    int j    = l >> 3;
    int ncol = j % npass;
    int panel= (j / npass) * 8 + xcd;
    if (panel >= MT) return;
    int m0 = panel * 128;

    int wm = (wave >> 1) * 64, wn = (wave & 1) * 64;
    int fr = lane & 15, fq = lane >> 4;          // fragment row / k-chunk
    int colq = lane & 15, rq = (lane >> 4) * 4;  // epilogue C/D mapping

    const unsigned short* Abase = Ag + (size_t)m0 * K;
    const unsigned short* Bbase = Bg + (size_t)ncol * 128 * K;

    // staging: chunk-slot ids for the two issues; global k-chunk is XOR-swizzled
    int c0 = tid, c1 = 256 + tid;
    size_t aoff0 = (size_t)(c0 >> 2) * K + 8 * ((c0 & 3) ^ ((c0 >> 3) & 3));
    size_t aoff1 = (size_t)(c1 >> 2) * K + 8 * ((c1 & 3) ^ ((c1 >> 3) & 3));

    // fragment LDS offsets (in shorts): slot(r, q) = 4r + (q ^ ((r&15)>>1 &3))
    int fswz = 8 * (fq ^ ((fr >> 1) & 3));

#define STAGEK(bi, kt_) do {                                                   \
        int _b  = (bi) * 8192;                                                 \
        int _k0 = (kt_) * 32;                                                  \
        GLD_LDS16(Abase + aoff0 + _k0, &smem[_b + c0 * 8]);                    \
        GLD_LDS16(Abase + aoff1 + _k0, &smem[_b + c1 * 8]);                    \
        GLD_LDS16(Bbase + aoff0 + _k0, &smem[_b + 4096 + c0 * 8]);             \
        GLD_LDS16(Bbase + aoff1 + _k0, &smem[_b + 4096 + c1 * 8]);             \
    } while (0)

#define SBAR() do {                                                            \
        __builtin_amdgcn_sched_barrier(0);                                     \
        __builtin_amdgcn_s_barrier();                                          \
        __builtin_amdgcn_sched_barrier(0);                                     \
    } while (0)

    f32x4 acc[4][4];
#pragma unroll
    for (int i = 0; i < 4; ++i)
#pragma unroll
        for (int jj = 0; jj < 4; ++jj)
            acc[i][jj] = (f32x4){0.f, 0.f, 0.f, 0.f};

    int NT = K >> 5;            // K/32 (10 or 20), always >= 2
    STAGEK(0, 0);               // prologue: depth-2 pipeline fill
    STAGEK(1, 1);

    for (int kt = 0; kt < NT; ++kt) {
        int base = (kt % 3) * 8192;

        // tile kt is the oldest 4 of <=8 outstanding loads
        if (kt + 1 < NT) {
            asm volatile("s_waitcnt vmcnt(4)" ::: "memory");
        } else {
            asm volatile("s_waitcnt vmcnt(0)" ::: "memory");
        }
        SBAR();   // tile kt visible to all; buffer (kt+2)%3 free for reuse

        if (kt + 2 < NT) STAGEK((kt + 2) % 3, kt + 2);

        bf16x8 af[4], bfv[4];
#pragma unroll
        for (int i = 0; i < 4; ++i) {
            af[i]  = *(const bf16x8*)&smem[base + (wm + i * 16 + fr) * 32 + fswz];
            bfv[i] = *(const bf16x8*)&smem[base + 4096 + (wn + i * 16 + fr) * 32 + fswz];
        }
#pragma unroll
        for (int i = 0; i < 4; ++i)
#pragma unroll
            for (int jj = 0; jj < 4; ++jj)
                acc[i][jj] = __builtin_amdgcn_mfma_f32_16x16x32_bf16(
                    af[i], bfv[jj], acc[i][jj], 0, 0, 0);
    }
    __syncthreads();   // epilogue reuses buffer 0; ensure all reads retired

    // ---- epilogue: bias + relu + bf16, LDS bounce for coalesced stores ----
#pragma unroll
    for (int ch = 0; ch < 2; ++ch) {
        if ((wn >> 6) == ch) {              // waves owning this 64-col half
#pragma unroll
            for (int jj = 0; jj < 4; ++jj) {
                int lc  = jj * 16 + colq;                  // 0..63
                int col = ncol * 128 + wn + jj * 16 + colq;
                float bv = (col < bias_n) ? bias[col] : 0.f;
#pragma unroll
                for (int i = 0; i < 4; ++i) {
                    int rbase = wm + i * 16 + rq;
#pragma unroll
                    for (int r = 0; r < 4; ++r) {
                        float v = fmaxf(acc[i][jj][r] + bv, 0.f);
                        smem[(rbase + r) * 64 + lc] = f2b(v);
                    }
                }
            }
        }
        __syncthreads();
        int cbase = ncol * 128 + ch * 64;
        if (cbase < store_cols) {
#pragma unroll
            for (int i = 0; i < 4; ++i) {
                int idx = i * 256 + tid;        // 0..1023 uint4 chunks
                int row = idx >> 3, c8 = idx & 7;
                *(uint4*)&C[(size_t)(m0 + row) * ldc + cbase + c8 * 8] =
                    *(uint4*)&smem[row * 64 + c8 * 8];
            }
        }
        __syncthreads();
    }
#undef STAGEK
#undef SBAR
}

// ---------------------------------------------------------------------------
// pool v2: g[gid] = sum of Hb rows (bf16, stride KP) with batch==gid.
// 4 waves split the node range (stride 4); lanes 0..39 each own an 8-feat
// chunk via u16x8 vector loads; LDS reduce of the 4 wave partials.
// ---------------------------------------------------------------------------
__global__ __launch_bounds__(256) void k_pool(
    const unsigned short* __restrict__ H, const int* __restrict__ batch,
    float* __restrict__ g, int n)
{
    __shared__ float red[3][KP];
    int gid  = blockIdx.x;
    int tid  = threadIdx.x;
    int wave = tid >> 6, lane = tid & 63;
    int c0   = lane * 8;                    // lanes 0..39 active (KP/8 = 40)

    int lo = 0, hi = n;
    while (lo < hi) { int mid = (lo + hi) >> 1; if (batch[mid] < gid) lo = mid + 1; else hi = mid; }
    int start = lo;
    hi = n;
    while (lo < hi) { int mid = (lo + hi) >> 1; if (batch[mid] < gid + 1) lo = mid + 1; else hi = mid; }
    int end = lo;

    float acc[8] = {0.f, 0.f, 0.f, 0.f, 0.f, 0.f, 0.f, 0.f};
    if (c0 < KP) {
        for (int v = start + wave; v < end; v += 4) {
            u16x8 hv = *(const u16x8*)&H[(size_t)v * KP + c0];
#pragma unroll
            for (int j = 0; j < 8; ++j) acc[j] += b2f(hv[j]);
        }
        if (wave != 0) {
#pragma unroll
            for (int j = 0; j < 8; ++j) red[wave - 1][c0 + j] = acc[j];
        }
    }
    __syncthreads();
    if (wave == 0 && c0 < NFEAT) {
#pragma unroll
        for (int j = 0; j < 8; ++j) {
            if (c0 + j < NFEAT) {
                float s = acc[j] + red[0][c0 + j] + red[1][c0 + j] + red[2][c0 + j];
                g[(size_t)gid * NFEAT + c0 + j] = s;
            }
        }
    }
}

// ---------------------------------------------------------------------------
// out = g @ Wfc + bfc   (2048x300 @ 300x300), fp32, ILP-4 partial sums
// ---------------------------------------------------------------------------
__global__ __launch_bounds__(256) void k_final(
    const float* __restrict__ g, const float* __restrict__ Wfc,
    const float* __restrict__ bfc, float* __restrict__ out)
{
    int idx = blockIdx.x * blockDim.x + threadIdx.x;
    if (idx >= NGRAPH * NFEAT) return;
    int r = idx / NFEAT, c = idx % NFEAT;
    const float* gr = &g[(size_t)r * NFEAT];
    float s0 = 0.f, s1 = 0.f, s2 = 0.f, s3 = 0.f;
    for (int k = 0; k < NFEAT; k += 4) {     // 300 % 4 == 0
        s0 = fmaf(gr[k],     Wfc[(size_t)(k)     * NFEAT + c], s0);
        s1 = fmaf(gr[k + 1], Wfc[(size_t)(k + 1) * NFEAT + c], s1);
        s2 = fmaf(gr[k + 2], Wfc[(size_t)(k + 2) * NFEAT + c], s2);
        s3 = fmaf(gr[k + 3], Wfc[(size_t)(k + 3) * NFEAT + c], s3);
    }
    out[idx] = bfc[c] + ((s0 + s1) + (s2 + s3));
}

extern "C" void kernel_launch(void* const* d_in, const int* in_sizes, int n_in,
                              void* d_out, int out_size, void* d_ws, size_t ws_size,
                              hipStream_t stream)
{
    const float* x    = (const float*)d_in[0];
    const int*   ei   = (const int*)  d_in[1];
    const int*   ea   = (const int*)  d_in[2];
    const int*   batch= (const int*)  d_in[3];
    const float* emb1 = (const float*)d_in[4];
    const float* emb2 = (const float*)d_in[5];
    const float* W1   = (const float*)d_in[6];
    const float* b1   = (const float*)d_in[7];
    const float* W2   = (const float*)d_in[8];
    const float* b2   = (const float*)d_in[9];
    const float* Wfc  = (const float*)d_in[10];
    const float* bfc  = (const float*)d_in[11];
    float* out = (float*)d_out;

    int n = in_sizes[0] / NFEAT;   // 100000
    int E = in_sizes[1] / 2;       // 200000
    int MT   = (n + 127) / 128;    // 782
    int Mpad = MT * 128;           // 100096
    int MT8  = ((MT + 7) / 8) * 8; // 784 (XCD-swizzle padding)

    // ---- workspace layout ----
    char* p = (char*)d_ws;
    auto take = [&](size_t bytes) { char* r = p; p += (bytes + 255) & ~(size_t)255; return r; };
    unsigned short* T    = (unsigned short*)take((size_t)Mpad * N1P * 2); // 128.1 MB
    unsigned short* xb   = T;                                             // overlay (dead before T)
    unsigned short* Ab   = (unsigned short*)take((size_t)Mpad * KP * 2);  // 64.06 MB
    unsigned short* Hb   = (unsigned short*)take((size_t)Mpad * KP * 2);  // 64.06 MB
    unsigned short* Wt1  = (unsigned short*)take((size_t)N1P * KP * 2);
    unsigned short* Wt2  = (unsigned short*)take((size_t)N2P * N1P * 2);
    float*          embc = (float*)take((size_t)NTD * KP * 4);
    float*          g    = (float*)take((size_t)NGRAPH * NFEAT * 4);
    int*            deg  = (int*)take((size_t)n * 4);
    int*            offs = (int*)take((size_t)(n + 1) * 4);
    int*            curs = (int*)take((size_t)n * 4);
    int*            erec = (int*)take((size_t)E * 4);
    int*            bsum = (int*)take(256 * 4);

    dim3 blk(256);
    int chunkThreads = Mpad * (KP / 8);
    int chunkBlocks  = (chunkThreads + 255) / 256;
    int nb = (n + SCAN_B - 1) / SCAN_B;

    // ---- one-time prep (per call) ----
    k_cvtW<<<(N1P * KP + 255) / 256, blk, 0, stream>>>(W1, Wt1, NFEAT, 600, KP, N1P);
    k_cvtW<<<(N2P * N1P + 255) / 256, blk, 0, stream>>>(W2, Wt2, 600, NFEAT, N1P, N2P);
    k_embc<<<(NTD * KP + 255) / 256, blk, 0, stream>>>(emb1, emb2, embc);
    k_cvtX<<<chunkBlocks, blk, 0, stream>>>(x, xb, n, Mpad);

    // ---- CSR build ----
    k_zero <<<(n + 255) / 256, blk, 0, stream>>>(deg, n);
    k_deg  <<<(E + 255) / 256, blk, 0, stream>>>(ei, deg, E);
    k_scan1<<<nb, blk, 0, stream>>>(deg, offs, bsum, n);
    k_scan2<<<1, 64, 0, stream>>>(bsum, nb, offs);
    k_scan3<<<(n + 255) / 256, blk, 0, stream>>>(deg, offs, bsum, curs, n);
    k_fill <<<(E + 255) / 256, blk, 0, stream>>>(ei, ea, curs, erec, E);

    // ---- layer 1 ----
    k_aggr<<<chunkBlocks, blk, 0, stream>>>(xb, offs, erec, embc, Ab, n, Mpad);
    k_gemm<<<MT8 * (N1P / 128), blk, 0, stream>>>(Ab, Wt1, b1, 600, T, N1P, N1P, KP, N1P / 128, MT);
    k_gemm<<<MT8 * (N2P / 128), blk, 0, stream>>>(T, Wt2, b2, NFEAT, Hb, KP, KP, N1P, N2P / 128, MT);

    // ---- layer 2 ----
    k_aggr<<<chunkBlocks, blk, 0, stream>>>(Hb, offs, erec, embc, Ab, n, Mpad);
    k_gemm<<<MT8 * (N1P / 128), blk, 0, stream>>>(Ab, Wt1, b1, 600, T, N1P, N1P, KP, N1P / 128, MT);
    k_gemm<<<MT8 * (N2P / 128), blk, 0, stream>>>(T, Wt2, b2, NFEAT, Hb, KP, KP, N1P, N2P / 128, MT);

    // ---- pool + final ----
    k_pool <<<NGRAPH, blk, 0, stream>>>(Hb, batch, g, n);
    k_final<<<(NGRAPH * NFEAT + 255) / 256, blk, 0, stream>>>(g, Wfc, bfc, out);
}

// Round 7
// 659.613 us; speedup vs baseline: 1.3155x; 1.0108x over previous
//
#include <hip/hip_runtime.h>
#include <hip/hip_bf16.h>

#define NFEAT 300
#define KP 320           // padded feature stride (bf16 rows)
#define NGRAPH 2048
#define N1P 640          // padded N for GEMM1 (600 -> 640)
#define N2P 384          // padded N for GEMM2 (300 -> 384)
#define NTD 18           // bond_type(6) * bond_dir(3)
#define SCAN_B 2048      // elements per scan block (256 thr * 8)

typedef __bf16 bf16x8 __attribute__((ext_vector_type(8)));
typedef float  f32x4  __attribute__((ext_vector_type(4)));
typedef unsigned short u16x8 __attribute__((ext_vector_type(8)));

__device__ __forceinline__ unsigned short f2b(float v) {
    union { float f; unsigned u; } x; x.f = v;
    unsigned r = x.u + 0x7fff + ((x.u >> 16) & 1);   // RNE
    return (unsigned short)(r >> 16);
}
__device__ __forceinline__ float b2f(unsigned short u) {
    union { unsigned u; float f; } x; x.u = ((unsigned)u) << 16;
    return x.f;
}

#define GLD_LDS16(g, l)                                                        \
    __builtin_amdgcn_global_load_lds(                                          \
        (const __attribute__((address_space(1))) void*)(g),                    \
        (__attribute__((address_space(3))) void*)(l), 16, 0, 0)

// ---------------------------------------------------------------------------
// Fused prep (R7): cvtW1 | cvtW2 | embc | cvtX | zero(deg) -- five mutually
// independent jobs, one dispatch, partitioned by blockIdx range.
// ---------------------------------------------------------------------------
__device__ __forceinline__ void cvtW_body(
    const float* __restrict__ W, unsigned short* __restrict__ Wt,
    int rows, int cols, int Kpad, int Npad, int t)
{
    if (t >= Npad * Kpad) return;
    int nn = t / Kpad, k = t % Kpad;
    float v = (k < rows && nn < cols) ? W[(size_t)k * cols + nn] : 0.f;
    Wt[t] = f2b(v);
}

__global__ __launch_bounds__(256) void k_prep(
    const float* __restrict__ W1, unsigned short* __restrict__ Wt1,
    const float* __restrict__ W2, unsigned short* __restrict__ Wt2,
    const float* __restrict__ emb1, const float* __restrict__ emb2,
    float* __restrict__ embc,
    const float* __restrict__ x, unsigned short* __restrict__ xb,
    int* __restrict__ deg, int n, int Mpad,
    int b1e, int b2e, int b3e, int b4e)
{
    int b = blockIdx.x, tid = threadIdx.x;
    if (b < b1e) {                                   // cvtW1: [640 x 320]
        cvtW_body(W1, Wt1, NFEAT, 600, KP, N1P, b * 256 + tid);
    } else if (b < b2e) {                            // cvtW2: [384 x 640]
        cvtW_body(W2, Wt2, 600, NFEAT, N1P, N2P, (b - b1e) * 256 + tid);
    } else if (b < b3e) {                            // embc: [18 x 320]
        int t = (b - b2e) * 256 + tid;
        if (t < NTD * KP) {
            int td = t / KP, c = t % KP;
            int t1 = td / 3, d = td % 3;
            embc[t] = (c < NFEAT) ? emb1[t1 * NFEAT + c] + emb2[d * NFEAT + c] : 0.f;
        }
    } else if (b < b4e) {                            // cvtX: fp32 -> bf16 [Mpad x 320]
        int idx = (b - b3e) * 256 + tid;
        if (idx < Mpad * (KP / 8)) {
            int row = idx / (KP / 8), c0 = (idx % (KP / 8)) * 8;
            unsigned short o[8];
#pragma unroll
            for (int j = 0; j < 8; ++j) {
                int col = c0 + j;
                float v = (row < n && col < NFEAT) ? x[(size_t)row * NFEAT + col] : 0.f;
                o[j] = f2b(v);
            }
            *(uint4*)&xb[(size_t)row * KP + c0] = *(uint4*)o;
        }
    } else {                                         // zero deg
        int i = (b - b4e) * 256 + tid;
        if (i < n) deg[i] = 0;
    }
}

// ---------------------------------------------------------------------------
// CSR build: deg -> exclusive-scan offsets -> cursor fill, packed records
// ---------------------------------------------------------------------------
__global__ __launch_bounds__(256) void k_deg(
    const int* __restrict__ ei, int* __restrict__ deg, int E)
{
    int e = blockIdx.x * blockDim.x + threadIdx.x;
    if (e >= E) return;
    atomicAdd(&deg[ei[E + e]], 1);
}

__global__ __launch_bounds__(256) void k_scan1(
    const int* __restrict__ deg, int* __restrict__ offsets,
    int* __restrict__ bsum, int n)
{
    __shared__ int sh[256];
    int tid = threadIdx.x;
    int base = blockIdx.x * SCAN_B + tid * 8;
    int v[8], run = 0;
#pragma unroll
    for (int j = 0; j < 8; ++j) {
        int i = base + j;
        v[j] = (i < n) ? deg[i] : 0;
        run += v[j];
        v[j] = run;
    }
    sh[tid] = run;
    __syncthreads();
    for (int off = 1; off < 256; off <<= 1) {
        int t = (tid >= off) ? sh[tid - off] : 0;
        __syncthreads();
        sh[tid] += t;
        __syncthreads();
    }
    int excl = sh[tid] - run;
#pragma unroll
    for (int j = 0; j < 8; ++j) {
        int i = base + j;
        if (i < n) offsets[i + 1] = excl + v[j];
    }
    if (tid == 0) bsum[blockIdx.x] = sh[255];
}

// R7: k_scan2 eliminated -- the <=49-element bsum prefix is recomputed
// inline per thread (L1-broadcast loads, trivial); bsum stays raw.
__global__ __launch_bounds__(256) void k_scan3(
    const int* __restrict__ deg, int* __restrict__ offsets,
    const int* __restrict__ bsum, int* __restrict__ cursor, int n)
{
    int i = blockIdx.x * blockDim.x + threadIdx.x;
    if (i == 0) offsets[0] = 0;
    if (i >= n) return;
    int nbi = i / SCAN_B;
    int pre = 0;
    for (int j = 0; j < nbi; ++j) pre += bsum[j];
    int fin = offsets[i + 1] + pre;
    offsets[i + 1] = fin;
    cursor[i] = fin - deg[i];
}

__global__ __launch_bounds__(256) void k_fill(
    const int* __restrict__ ei, const int* __restrict__ ea,
    int* __restrict__ cursor, int* __restrict__ edgerec, int E)
{
    int e = blockIdx.x * blockDim.x + threadIdx.x;
    if (e >= E) return;
    int dst = ei[E + e];
    int pos = atomicAdd(&cursor[dst], 1);
    int src = ei[e];
    int td  = ea[2 * e] * 3 + ea[2 * e + 1];
    edgerec[pos] = src | (td << 20);
}

// ---------------------------------------------------------------------------
// Gather-side aggregation (R7: 32 B / thread -- 16 cols per thread halves
// the per-vertex redundant offsets/edgerec metadata loads):
// Ab[v] = bf16( h[v] + embc[0] + sum_{e: dst=v} ( h[src_e] + embc[td_e] ) )
// ---------------------------------------------------------------------------
__global__ __launch_bounds__(256) void k_aggr(
    const unsigned short* __restrict__ h,
    const int* __restrict__ offsets, const int* __restrict__ edgerec,
    const float* __restrict__ embc,
    unsigned short* __restrict__ Ab, int n, int Mpad)
{
    int idx = blockIdx.x * blockDim.x + threadIdx.x;
    if (idx >= Mpad * (KP / 16)) return;
    int v = idx / (KP / 16), c0 = (idx % (KP / 16)) * 16;
    unsigned short* outp = &Ab[(size_t)v * KP + c0];
    if (v >= n) {
        *(uint4*)outp       = make_uint4(0, 0, 0, 0);
        *(uint4*)(outp + 8) = make_uint4(0, 0, 0, 0);
        return;
    }
    float acc[16];
    const unsigned short* hr = &h[(size_t)v * KP + c0];
    u16x8 hv0 = *(const u16x8*)hr;
    u16x8 hv1 = *(const u16x8*)(hr + 8);
    const float* e0 = embc + c0;
#pragma unroll
    for (int j = 0; j < 8; ++j) {
        acc[j]     = b2f(hv0[j]) + e0[j];
        acc[8 + j] = b2f(hv1[j]) + e0[8 + j];
    }

    int beg = offsets[v], end = offsets[v + 1];
    for (int e = beg; e < end; ++e) {
        int rec = edgerec[e];
        int src = rec & 0xFFFFF;
        int td  = rec >> 20;
        const unsigned short* hs = &h[(size_t)src * KP + c0];
        u16x8 s0 = *(const u16x8*)hs;
        u16x8 s1 = *(const u16x8*)(hs + 8);
        const float* ee = embc + td * KP + c0;
#pragma unroll
        for (int j = 0; j < 8; ++j) {
            acc[j]     += b2f(s0[j]) + ee[j];
            acc[8 + j] += b2f(s1[j]) + ee[8 + j];
        }
    }
    unsigned short o[16];
#pragma unroll
    for (int j = 0; j < 16; ++j) o[j] = f2b(acc[j]);
    *(uint4*)outp       = *(uint4*)o;
    *(uint4*)(outp + 8) = *(uint4*)(o + 8);
}

// ---------------------------------------------------------------------------
// bf16 MFMA GEMM -- EXACT v4 structure (proven 76-77 us / 26% MfmaUtil).
//
// Model (R6): per block K-step ~1000 cy wall at ~2 resident blocks; LDS
// read traffic 32 KB/step at ~85 B/cy (~385 cy) + stage writes + barrier
// pacing puts the LDS port at 70-100% busy -- measured local floor for
// this 2x2-wave/128^2 geometry. All within-structure levers measured:
// barrier halving +9% (R2), counted-vmcnt depth-2 +10% (R3), B off-LDS
// -60% (R4, worse pipe). Past this requires 256^2/8-wave geometry.
//
// T3+T4 counted-vmcnt pipeline: triple-buffered LDS (3 x 16 KB), depth-2
// prefetch, ONE raw s_barrier per K-step with counted s_waitcnt vmcnt(4)
// (vmcnt(0) only on the last iteration). Hazard audit in R3 notes.
// Staging lane L fetches row (L>>2), k-chunk ((L&3) ^ ((L>>3)&3)); chunk
// (r,c) lands at LDS slot 4r + (c ^ ((r>>1)&3)); fragment ds_read_b128
// phases sweep bank groups conflict-free (2-way only, free).
// Epilogue bounces accumulators through LDS for coalesced uint4 stores.
// C = relu(A @ Bt^T + bias). A [Mpad x K] rm bf16, Bt [N x K] rm bf16.
// ---------------------------------------------------------------------------
__global__ __launch_bounds__(256) void k_gemm(
    const unsigned short* __restrict__ Ag, const unsigned short* __restrict__ Bg,
    const float* __restrict__ bias, int bias_n,
    unsigned short* __restrict__ C, int ldc, int store_cols,
    int K, int npass, int MT)
{
    __shared__ unsigned short smem[24576];  // 48 KB: 3 buffers of (sA 4K | sB 4K shorts)

    int tid  = threadIdx.x;
    int lane = tid & 63, wave = tid >> 6;

    // XCD-swizzle: same panel -> same XCD for all npass column tiles
    int l    = blockIdx.x;
    int xcd  = l & 7;
    int j    = l >> 3;
    int ncol = j % npass;
    int panel= (j / npass) * 8 + xcd;
    if (panel >= MT) return;
    int m0 = panel * 128;

    int wm = (wave >> 1) * 64, wn = (wave & 1) * 64;
    int fr = lane & 15, fq = lane >> 4;          // fragment row / k-chunk
    int colq = lane & 15, rq = (lane >> 4) * 4;  // epilogue C/D mapping

    const unsigned short* Abase = Ag + (size_t)m0 * K;
    const unsigned short* Bbase = Bg + (size_t)ncol * 128 * K;

    // staging: chunk-slot ids for the two issues; global k-chunk is XOR-swizzled
    int c0 = tid, c1 = 256 + tid;
    size_t aoff0 = (size_t)(c0 >> 2) * K + 8 * ((c0 & 3) ^ ((c0 >> 3) & 3));
    size_t aoff1 = (size_t)(c1 >> 2) * K + 8 * ((c1 & 3) ^ ((c1 >> 3) & 3));

    // fragment LDS offsets (in shorts): slot(r, q) = 4r + (q ^ ((r&15)>>1 &3))
    int fswz = 8 * (fq ^ ((fr >> 1) & 3));

#define STAGEK(bi, kt_) do {                                                   \
        int _b  = (bi) * 8192;                                                 \
        int _k0 = (kt_) * 32;                                                  \
        GLD_LDS16(Abase + aoff0 + _k0, &smem[_b + c0 * 8]);                    \
        GLD_LDS16(Abase + aoff1 + _k0, &smem[_b + c1 * 8]);                    \
        GLD_LDS16(Bbase + aoff0 + _k0, &smem[_b + 4096 + c0 * 8]);             \
        GLD_LDS16(Bbase + aoff1 + _k0, &smem[_b + 4096 + c1 * 8]);             \
    } while (0)

#define SBAR() do {                                                            \
        __builtin_amdgcn_sched_barrier(0);                                     \
        __builtin_amdgcn_s_barrier();                                          \
        __builtin_amdgcn_sched_barrier(0);                                     \
    } while (0)

    f32x4 acc[4][4];
#pragma unroll
    for (int i = 0; i < 4; ++i)
#pragma unroll
        for (int jj = 0; jj < 4; ++jj)
            acc[i][jj] = (f32x4){0.f, 0.f, 0.f, 0.f};

    int NT = K >> 5;            // K/32 (10 or 20), always >= 2
    STAGEK(0, 0);               // prologue: depth-2 pipeline fill
    STAGEK(1, 1);

    for (int kt = 0; kt < NT; ++kt) {
        int base = (kt % 3) * 8192;

        // tile kt is the oldest 4 of <=8 outstanding loads
        if (kt + 1 < NT) {
            asm volatile("s_waitcnt vmcnt(4)" ::: "memory");
        } else {
            asm volatile("s_waitcnt vmcnt(0)" ::: "memory");
        }
        SBAR();   // tile kt visible to all; buffer (kt+2)%3 free for reuse

        if (kt + 2 < NT) STAGEK((kt + 2) % 3, kt + 2);

        bf16x8 af[4], bfv[4];
#pragma unroll
        for (int i = 0; i < 4; ++i) {
            af[i]  = *(const bf16x8*)&smem[base + (wm + i * 16 + fr) * 32 + fswz];
            bfv[i] = *(const bf16x8*)&smem[base + 4096 + (wn + i * 16 + fr) * 32 + fswz];
        }
#pragma unroll
        for (int i = 0; i < 4; ++i)
#pragma unroll
            for (int jj = 0; jj < 4; ++jj)
                acc[i][jj] = __builtin_amdgcn_mfma_f32_16x16x32_bf16(
                    af[i], bfv[jj], acc[i][jj], 0, 0, 0);
    }
    __syncthreads();   // epilogue reuses buffer 0; ensure all reads retired

    // ---- epilogue: bias + relu + bf16, LDS bounce for coalesced stores ----
#pragma unroll
    for (int ch = 0; ch < 2; ++ch) {
        if ((wn >> 6) == ch) {              // waves owning this 64-col half
#pragma unroll
            for (int jj = 0; jj < 4; ++jj) {
                int lc  = jj * 16 + colq;                  // 0..63
                int col = ncol * 128 + wn + jj * 16 + colq;
                float bv = (col < bias_n) ? bias[col] : 0.f;
#pragma unroll
                for (int i = 0; i < 4; ++i) {
                    int rbase = wm + i * 16 + rq;
#pragma unroll
                    for (int r = 0; r < 4; ++r) {
                        float v = fmaxf(acc[i][jj][r] + bv, 0.f);
                        smem[(rbase + r) * 64 + lc] = f2b(v);
                    }
                }
            }
        }
        __syncthreads();
        int cbase = ncol * 128 + ch * 64;
        if (cbase < store_cols) {
#pragma unroll
            for (int i = 0; i < 4; ++i) {
                int idx = i * 256 + tid;        // 0..1023 uint4 chunks
                int row = idx >> 3, c8 = idx & 7;
                *(uint4*)&C[(size_t)(m0 + row) * ldc + cbase + c8 * 8] =
                    *(uint4*)&smem[row * 64 + c8 * 8];
            }
        }
        __syncthreads();
    }
#undef STAGEK
#undef SBAR
}

// ---------------------------------------------------------------------------
// pool v2: g[gid] = sum of Hb rows (bf16, stride KP) with batch==gid.
// 4 waves split the node range (stride 4); lanes 0..39 each own an 8-feat
// chunk via u16x8 vector loads; LDS reduce of the 4 wave partials.
// ---------------------------------------------------------------------------
__global__ __launch_bounds__(256) void k_pool(
    const unsigned short* __restrict__ H, const int* __restrict__ batch,
    float* __restrict__ g, int n)
{
    __shared__ float red[3][KP];
    int gid  = blockIdx.x;
    int tid  = threadIdx.x;
    int wave = tid >> 6, lane = tid & 63;
    int c0   = lane * 8;                    // lanes 0..39 active (KP/8 = 40)

    int lo = 0, hi = n;
    while (lo < hi) { int mid = (lo + hi) >> 1; if (batch[mid] < gid) lo = mid + 1; else hi = mid; }
    int start = lo;
    hi = n;
    while (lo < hi) { int mid = (lo + hi) >> 1; if (batch[mid] < gid + 1) lo = mid + 1; else hi = mid; }
    int end = lo;

    float acc[8] = {0.f, 0.f, 0.f, 0.f, 0.f, 0.f, 0.f, 0.f};
    if (c0 < KP) {
        for (int v = start + wave; v < end; v += 4) {
            u16x8 hv = *(const u16x8*)&H[(size_t)v * KP + c0];
#pragma unroll
            for (int j = 0; j < 8; ++j) acc[j] += b2f(hv[j]);
        }
        if (wave != 0) {
#pragma unroll
            for (int j = 0; j < 8; ++j) red[wave - 1][c0 + j] = acc[j];
        }
    }
    __syncthreads();
    if (wave == 0 && c0 < NFEAT) {
#pragma unroll
        for (int j = 0; j < 8; ++j) {
            if (c0 + j < NFEAT) {
                float s = acc[j] + red[0][c0 + j] + red[1][c0 + j] + red[2][c0 + j];
                g[(size_t)gid * NFEAT + c0 + j] = s;
            }
        }
    }
}

// ---------------------------------------------------------------------------
// out = g @ Wfc + bfc   (2048x300 @ 300x300), fp32, ILP-4 partial sums
// ---------------------------------------------------------------------------
__global__ __launch_bounds__(256) void k_final(
    const float* __restrict__ g, const float* __restrict__ Wfc,
    const float* __restrict__ bfc, float* __restrict__ out)
{
    int idx = blockIdx.x * blockDim.x + threadIdx.x;
    if (idx >= NGRAPH * NFEAT) return;
    int r = idx / NFEAT, c = idx % NFEAT;
    const float* gr = &g[(size_t)r * NFEAT];
    float s0 = 0.f, s1 = 0.f, s2 = 0.f, s3 = 0.f;
    for (int k = 0; k < NFEAT; k += 4) {     // 300 % 4 == 0
        s0 = fmaf(gr[k],     Wfc[(size_t)(k)     * NFEAT + c], s0);
        s1 = fmaf(gr[k + 1], Wfc[(size_t)(k + 1) * NFEAT + c], s1);
        s2 = fmaf(gr[k + 2], Wfc[(size_t)(k + 2) * NFEAT + c], s2);
        s3 = fmaf(gr[k + 3], Wfc[(size_t)(k + 3) * NFEAT + c], s3);
    }
    out[idx] = bfc[c] + ((s0 + s1) + (s2 + s3));
}

extern "C" void kernel_launch(void* const* d_in, const int* in_sizes, int n_in,
                              void* d_out, int out_size, void* d_ws, size_t ws_size,
                              hipStream_t stream)
{
    const float* x    = (const float*)d_in[0];
    const int*   ei   = (const int*)  d_in[1];
    const int*   ea   = (const int*)  d_in[2];
    const int*   batch= (const int*)  d_in[3];
    const float* emb1 = (const float*)d_in[4];
    const float* emb2 = (const float*)d_in[5];
    const float* W1   = (const float*)d_in[6];
    const float* b1   = (const float*)d_in[7];
    const float* W2   = (const float*)d_in[8];
    const float* b2   = (const float*)d_in[9];
    const float* Wfc  = (const float*)d_in[10];
    const float* bfc  = (const float*)d_in[11];
    float* out = (float*)d_out;

    int n = in_sizes[0] / NFEAT;   // 100000
    int E = in_sizes[1] / 2;       // 200000
    int MT   = (n + 127) / 128;    // 782
    int Mpad = MT * 128;           // 100096
    int MT8  = ((MT + 7) / 8) * 8; // 784 (XCD-swizzle padding)

    // ---- workspace layout ----
    char* p = (char*)d_ws;
    auto take = [&](size_t bytes) { char* r = p; p += (bytes + 255) & ~(size_t)255; return r; };
    unsigned short* T    = (unsigned short*)take((size_t)Mpad * N1P * 2); // 128.1 MB
    unsigned short* xb   = T;                                             // overlay (dead before T)
    unsigned short* Ab   = (unsigned short*)take((size_t)Mpad * KP * 2);  // 64.06 MB
    unsigned short* Hb   = (unsigned short*)take((size_t)Mpad * KP * 2);  // 64.06 MB
    unsigned short* Wt1  = (unsigned short*)take((size_t)N1P * KP * 2);
    unsigned short* Wt2  = (unsigned short*)take((size_t)N2P * N1P * 2);
    float*          embc = (float*)take((size_t)NTD * KP * 4);
    float*          g    = (float*)take((size_t)NGRAPH * NFEAT * 4);
    int*            deg  = (int*)take((size_t)n * 4);
    int*            offs = (int*)take((size_t)(n + 1) * 4);
    int*            curs = (int*)take((size_t)n * 4);
    int*            erec = (int*)take((size_t)E * 4);
    int*            bsum = (int*)take(256 * 4);

    dim3 blk(256);
    int nb = (n + SCAN_B - 1) / SCAN_B;

    // ---- fused prep: cvtW1 | cvtW2 | embc | cvtX | zero(deg) ----
    int nb1 = (N1P * KP + 255) / 256;            // 800
    int nb2 = (N2P * N1P + 255) / 256;           // 960
    int nb3 = (NTD * KP + 255) / 256;            // 23
    int nb4 = (Mpad * (KP / 8) + 255) / 256;     // 15640
    int nb5 = (n + 255) / 256;                   // 391
    int b1e = nb1, b2e = b1e + nb2, b3e = b2e + nb3, b4e = b3e + nb4;
    k_prep<<<b4e + nb5, blk, 0, stream>>>(W1, Wt1, W2, Wt2, emb1, emb2, embc,
                                          x, xb, deg, n, Mpad, b1e, b2e, b3e, b4e);

    // ---- CSR build (scan2 fused into scan3) ----
    k_deg  <<<(E + 255) / 256, blk, 0, stream>>>(ei, deg, E);
    k_scan1<<<nb, blk, 0, stream>>>(deg, offs, bsum, n);
    k_scan3<<<(n + 255) / 256, blk, 0, stream>>>(deg, offs, bsum, curs, n);
    k_fill <<<(E + 255) / 256, blk, 0, stream>>>(ei, ea, curs, erec, E);

    int aggrBlocks = (Mpad * (KP / 16) + 255) / 256;   // 32 B per thread

    // ---- layer 1 ----
    k_aggr<<<aggrBlocks, blk, 0, stream>>>(xb, offs, erec, embc, Ab, n, Mpad);
    k_gemm<<<MT8 * (N1P / 128), blk, 0, stream>>>(Ab, Wt1, b1, 600, T, N1P, N1P, KP, N1P / 128, MT);
    k_gemm<<<MT8 * (N2P / 128), blk, 0, stream>>>(T, Wt2, b2, NFEAT, Hb, KP, KP, N1P, N2P / 128, MT);

    // ---- layer 2 ----
    k_aggr<<<aggrBlocks, blk, 0, stream>>>(Hb, offs, erec, embc, Ab, n, Mpad);
    k_gemm<<<MT8 * (N1P / 128), blk, 0, stream>>>(Ab, Wt1, b1, 600, T, N1P, N1P, KP, N1P / 128, MT);
    k_gemm<<<MT8 * (N2P / 128), blk, 0, stream>>>(T, Wt2, b2, NFEAT, Hb, KP, KP, N1P, N2P / 128, MT);

    // ---- pool + final ----
    k_pool <<<NGRAPH, blk, 0, stream>>>(Hb, batch, g, n);
    k_final<<<(NGRAPH * NFEAT + 255) / 256, blk, 0, stream>>>(g, Wfc, bfc, out);
}